// Round 18
// baseline (225.411 us; speedup 1.0000x reference)
//
#include <hip/hip_runtime.h>
#include <hip/hip_bf16.h>

typedef __attribute__((ext_vector_type(8))) short bf16x8;
typedef __attribute__((ext_vector_type(4))) float f32x4;

#define B_ 2
#define S_ 2048
#define H_ 2048
#define NH_ 16
#define NKV_ 8
#define HD_ 128
#define M_ (B_ * S_)                   // 4096
#define NQKV_ ((NH_ + 2 * NKV_) * HD_) // 4096
#define QK_SCALE 0.08838834764831845f  // 128^-0.5

#define VMCNT(n) asm volatile("s_waitcnt vmcnt(" #n ")" ::: "memory")

__device__ __forceinline__ unsigned short f2bf(float f) {
  unsigned int u = __float_as_uint(f);
  u += 0x7fffu + ((u >> 16) & 1u);
  return (unsigned short)(u >> 16);
}
__device__ __forceinline__ float bf2f(unsigned short h) {
  return __uint_as_float(((unsigned int)h) << 16);
}
__device__ __forceinline__ unsigned int cvt_pk_bf16(float lo, float hi) {
  unsigned int r;
  asm("v_cvt_pk_bf16_f32 %0, %1, %2" : "=v"(r) : "v"(lo), "v"(hi));
  return r;
}
__device__ __forceinline__ void gload_lds16(const void* g, void* l) {
  __builtin_amdgcn_global_load_lds(
      (const __attribute__((address_space(1))) void*)g,
      (__attribute__((address_space(3))) void*)l, 16, 0, 0);
}

// -------- phase 1 (merged): rmsnorm + qkv_w convert + rope table ---------
#define CONV_QKVW_F4 ((NQKV_ * H_) / 4)  // 2097152
#define ROPE_N (B_ * S_ * 64)            // 262144
__global__ __launch_bounds__(256) void k_prep(
    const int* __restrict__ positions, const float* __restrict__ hidden,
    const float* __restrict__ ln_w, const float* __restrict__ qkv_w,
    unsigned short* __restrict__ xn, unsigned short* __restrict__ qkvw_bf,
    float* __restrict__ cos_t, float* __restrict__ sin_t) {
  __shared__ float red[4];
  const int t = threadIdx.x;
  if (blockIdx.x < M_) {
    const int m = blockIdx.x;
    const float4* row = (const float4*)(hidden + (size_t)m * H_);
    float4 v0 = row[t];
    float4 v1 = row[t + 256];
    float ss = v0.x * v0.x + v0.y * v0.y + v0.z * v0.z + v0.w * v0.w +
               v1.x * v1.x + v1.y * v1.y + v1.z * v1.z + v1.w * v1.w;
#pragma unroll
    for (int mk = 1; mk < 64; mk <<= 1) ss += __shfl_xor(ss, mk);
    if ((t & 63) == 0) red[t >> 6] = ss;
    __syncthreads();
    ss = red[0] + red[1] + red[2] + red[3];
    const float sc = rsqrtf(ss * (1.0f / H_) + 1e-6f);
    const float4* wv = (const float4*)ln_w;
    float4 w0 = wv[t], w1 = wv[t + 256];
    ushort4 o0, o1;
    o0.x = f2bf(v0.x * sc * w0.x);
    o0.y = f2bf(v0.y * sc * w0.y);
    o0.z = f2bf(v0.z * sc * w0.z);
    o0.w = f2bf(v0.w * sc * w0.w);
    o1.x = f2bf(v1.x * sc * w1.x);
    o1.y = f2bf(v1.y * sc * w1.y);
    o1.z = f2bf(v1.z * sc * w1.z);
    o1.w = f2bf(v1.w * sc * w1.w);
    ushort4* orow = (ushort4*)(xn + (size_t)m * H_);
    orow[t] = o0;
    orow[t + 256] = o1;
  } else {
    const int L = (blockIdx.x - M_) * 256 + t;
    const int stride = 2048 * 256;
    for (int i = L; i < CONV_QKVW_F4; i += stride) {
      float4 v = ((const float4*)qkv_w)[i];
      ushort4 o;
      o.x = f2bf(v.x);
      o.y = f2bf(v.y);
      o.z = f2bf(v.z);
      o.w = f2bf(v.w);
      ((ushort4*)qkvw_bf)[i] = o;
    }
    if (L < ROPE_N) {
      const int d = L & 63;
      const int bs = L >> 6;
      float pos = (float)positions[bs];
      float inv_freq = powf(10000.0f, -(float)(2 * d) * (1.0f / HD_));
      float ang = pos * inv_freq;
      cos_t[L] = cosf(ang);
      sin_t[L] = sinf(ang);
    }
  }
}

// ------ 256x256 2-phase GEMM (QKV): full-B register residency ------
template <int FMB>
__device__ __forceinline__ void load_a256(const unsigned short* sAb, int wm,
                                          int lr, int lg, bf16x8 (&af)[2][4]) {
#pragma unroll
  for (int kk = 0; kk < 2; ++kk) {
    const int pc = kk * 4 + lg;
#pragma unroll
    for (int i = 0; i < 4; ++i) {
      const int R = wm + (FMB + i) * 16 + lr;
      const int idx = ((R >> 6) & 1) * 8192 +
                      ((((R >> 7) << 6) | (R & 63)) << 6) +
                      ((pc ^ (R & 7)) << 3);
      af[kk][i] = *(const bf16x8*)&sAb[idx];
    }
  }
}
template <int FNB>
__device__ __forceinline__ void load_b256(const unsigned short* sBb, int wn,
                                          int lr, int lg, bf16x8 (&bfv)[2][2]) {
#pragma unroll
  for (int kk = 0; kk < 2; ++kk) {
    const int pc = kk * 4 + lg;
#pragma unroll
    for (int j = 0; j < 2; ++j) {
      const int R = wn + (FNB + j) * 16 + lr;
      const int idx = ((R >> 5) & 1) * 8192 +
                      ((((R >> 6) << 5) | (R & 31)) << 6) +
                      ((pc ^ (R & 7)) << 3);
      bfv[kk][j] = *(const bf16x8*)&sBb[idx];
    }
  }
}

template <int FMB, int FNB>
__device__ __forceinline__ void phase_mfma(const bf16x8 (&af)[2][4],
                                           const bf16x8 (&bfv)[2][2],
                                           f32x4 (&acc)[8][4]) {
#pragma unroll
  for (int kk = 0; kk < 2; ++kk)
#pragma unroll
    for (int i = 0; i < 4; ++i)
#pragma unroll
      for (int j = 0; j < 2; ++j)
        acc[FMB + i][FNB + j] = __builtin_amdgcn_mfma_f32_16x16x32_bf16(
            af[kk][i], bfv[kk][j], acc[FMB + i][FNB + j], 0, 0, 0);
}

__global__ __launch_bounds__(512, 2) void k_gemm256(
    const unsigned short* __restrict__ A, const unsigned short* __restrict__ Bt,
    unsigned short* __restrict__ C, int M, int N, int K) {
  __shared__ unsigned short sA[2][256 * 64];
  __shared__ unsigned short sB[2][256 * 64];
  const int tid = threadIdx.x;
  const int w = tid >> 6;
  const int l = tid & 63;
  const int lr = l & 15, lg = l >> 4;
  const int gx = gridDim.x;
  const int lin = blockIdx.y * gx + blockIdx.x;
  const int cpx = (gx * gridDim.y) >> 3;
  const int swz = (lin & 7) * cpx + (lin >> 3);
  const int m0 = (swz / gx) * 256, n0 = (swz % gx) * 256;
  const int wm = (w >> 2) * 128, wn = (w & 3) * 64;
  f32x4 acc[8][4] = {};

  auto stageA = [&](int t, int bufi, int h) {
    const int k0 = t * 64;
#pragma unroll
    for (int i = 0; i < 2; ++i) {
      const int L = i * 512 + tid;
      const int r = L >> 3;
      const int R = ((r >> 6) << 7) | (h << 6) | (r & 63);
      const int d = (L & 7) ^ (r & 7);
      gload_lds16(A + (size_t)(m0 + R) * K + k0 + d * 8,
                  (char*)sA[bufi] + h * 16384 +
                      (size_t)(i * 512 + w * 64) * 16);
    }
  };
  auto stageB = [&](int t, int bufi, int h) {
    const int k0 = t * 64;
#pragma unroll
    for (int i = 0; i < 2; ++i) {
      const int L = i * 512 + tid;
      const int r = L >> 3;
      const int R = ((r >> 5) << 6) | (h << 5) | (r & 31);
      const int d = (L & 7) ^ (r & 7);
      gload_lds16(Bt + (size_t)(n0 + R) * K + k0 + d * 8,
                  (char*)sB[bufi] + h * 16384 +
                      (size_t)(i * 512 + w * 64) * 16);
    }
  };

#define BARR()                          \
  __builtin_amdgcn_s_barrier();         \
  __builtin_amdgcn_sched_barrier(0)

  stageA(0, 0, 0);
  stageB(0, 0, 0);
  stageB(0, 0, 1);
  stageA(0, 0, 1);
  VMCNT(2);
  BARR();

  bf16x8 af[2][4];
  bf16x8 bfv0[2][2];
  bf16x8 bfv1[2][2];
  const int NT = K >> 6;
  for (int t = 0; t < NT; ++t) {
    const int bufi = t & 1;
    const int nb = bufi ^ 1;
    const bool st = (t + 1 < NT);
    load_a256<0>(sA[bufi], wm, lr, lg, af);
    load_b256<0>(sB[bufi], wn, lr, lg, bfv0);
    load_b256<2>(sB[bufi], wn, lr, lg, bfv1);
    if (st) {
      stageA(t + 1, nb, 0);
      stageB(t + 1, nb, 0);
    }
    __builtin_amdgcn_s_setprio(1);
    phase_mfma<0, 0>(af, bfv0, acc);
    phase_mfma<0, 2>(af, bfv1, acc);
    __builtin_amdgcn_s_setprio(0);
    if (st) {
      VMCNT(4);
    } else {
      VMCNT(0);
    }
    BARR();
    load_a256<4>(sA[bufi], wm, lr, lg, af);
    if (st) {
      stageB(t + 1, nb, 1);
      stageA(t + 1, nb, 1);
    }
    __builtin_amdgcn_s_setprio(1);
    phase_mfma<4, 2>(af, bfv1, acc);
    phase_mfma<4, 0>(af, bfv0, acc);
    __builtin_amdgcn_s_setprio(0);
    if (st) VMCNT(2);
    BARR();
  }

#pragma unroll
  for (int fm = 0; fm < 8; ++fm)
#pragma unroll
    for (int fn = 0; fn < 4; ++fn)
#pragma unroll
      for (int r = 0; r < 4; ++r) {
        const int row = m0 + wm + fm * 16 + lg * 4 + r;
        const int col = n0 + wn + fn * 16 + lr;
        C[(size_t)row * N + col] = f2bf(acc[fm][fn][r]);
      }
#undef BARR
}

// ------ 256x128 2-phase GEMM (O-proj: f32 out += resid) ------
template <int FMB>
__device__ __forceinline__ void load_ao(const unsigned short* sAb, int wm,
                                        int lr, int lg, bf16x8 (&af)[2][2]) {
#pragma unroll
  for (int kk = 0; kk < 2; ++kk) {
    const int pc = kk * 4 + lg;
#pragma unroll
    for (int i = 0; i < 2; ++i) {
      const int R = wm + (FMB + i) * 16 + lr;
      const int idx = ((R >> 5) & 1) * 8192 +
                      ((((R >> 6) << 5) | (R & 31)) << 6) +
                      ((pc ^ (R & 7)) << 3);
      af[kk][i] = *(const bf16x8*)&sAb[idx];
    }
  }
}
template <int FNB>
__device__ __forceinline__ void load_bo(const unsigned short* sBb, int wn,
                                        int lr, int lg, bf16x8 (&bfv)[2][2]) {
#pragma unroll
  for (int kk = 0; kk < 2; ++kk) {
    const int pc = kk * 4 + lg;
#pragma unroll
    for (int j = 0; j < 2; ++j) {
      const int R = wn + (FNB + j) * 16 + lr;
      const int idx = ((R >> 5) & 1) * 4096 +
                      ((((R >> 6) << 5) | (R & 31)) << 6) +
                      ((pc ^ (R & 7)) << 3);
      bfv[kk][j] = *(const bf16x8*)&sBb[idx];
    }
  }
}

template <int FMB, int FNB>
__device__ __forceinline__ void phase_mfma_o(const bf16x8 (&af)[2][2],
                                             const bf16x8 (&bfv)[2][2],
                                             f32x4 (&acc)[4][4]) {
#pragma unroll
  for (int kk = 0; kk < 2; ++kk)
#pragma unroll
    for (int i = 0; i < 2; ++i)
#pragma unroll
      for (int j = 0; j < 2; ++j)
        acc[FMB + i][FNB + j] = __builtin_amdgcn_mfma_f32_16x16x32_bf16(
            af[kk][i], bfv[kk][j], acc[FMB + i][FNB + j], 0, 0, 0);
}

__global__ __launch_bounds__(512, 1) void k_gemm_ores(
    const unsigned short* __restrict__ A, const unsigned short* __restrict__ Bt,
    float* __restrict__ Cout, const float* __restrict__ resid, int M, int N,
    int K) {
  __shared__ unsigned short sA[2][256 * 64];
  __shared__ unsigned short sB[2][128 * 64];
  const int tid = threadIdx.x;
  const int w = tid >> 6;
  const int l = tid & 63;
  const int lr = l & 15, lg = l >> 4;
  const int gx = gridDim.x;
  const int lin = blockIdx.y * gx + blockIdx.x;
  const int cpx = (gx * gridDim.y) >> 3;
  const int swz = (lin & 7) * cpx + (lin >> 3);
  const int m0 = (swz / gx) * 256, n0 = (swz % gx) * 128;
  const int wm = (w >> 1) * 64, wn = (w & 1) * 64;
  f32x4 acc[4][4] = {};

  auto stageAo = [&](int t, int bufi, int h) {
    const int k0 = t * 64;
#pragma unroll
    for (int i = 0; i < 2; ++i) {
      const int L = i * 512 + tid;
      const int r = L >> 3;
      const int R = ((r >> 5) << 6) | (h << 5) | (r & 31);
      const int d = (L & 7) ^ (r & 7);
      gload_lds16(A + (size_t)(m0 + R) * K + k0 + d * 8,
                  (char*)sA[bufi] + h * 16384 +
                      (size_t)(i * 512 + w * 64) * 16);
    }
  };
  auto stageBo = [&](int t, int bufi, int h) {
    const int k0 = t * 64;
    const int L = tid;
    const int r = L >> 3;
    const int R = ((r >> 5) << 6) | (h << 5) | (r & 31);
    const int d = (L & 7) ^ (r & 7);
    gload_lds16(Bt + (size_t)(n0 + R) * K + k0 + d * 8,
                (char*)sB[bufi] + h * 8192 + (size_t)(w * 64) * 16);
  };

#define BARR()                          \
  __builtin_amdgcn_s_barrier();         \
  __builtin_amdgcn_sched_barrier(0)

  stageAo(0, 0, 0);
  stageBo(0, 0, 0);
  stageBo(0, 0, 1);
  stageAo(0, 0, 1);
  VMCNT(2);
  BARR();

  bf16x8 af[2][2];
  bf16x8 bfv0[2][2];
  bf16x8 bfv1[2][2];
  const int NT = K >> 6;
  for (int t = 0; t < NT; ++t) {
    const int bufi = t & 1;
    const int nb = bufi ^ 1;
    const bool st = (t + 1 < NT);
    load_ao<0>(sA[bufi], wm, lr, lg, af);
    load_bo<0>(sB[bufi], wn, lr, lg, bfv0);
    load_bo<2>(sB[bufi], wn, lr, lg, bfv1);
    if (st) {
      stageAo(t + 1, nb, 0);
      stageBo(t + 1, nb, 0);
    }
    __builtin_amdgcn_s_setprio(1);
    phase_mfma_o<0, 0>(af, bfv0, acc);
    phase_mfma_o<0, 2>(af, bfv1, acc);
    __builtin_amdgcn_s_setprio(0);
    if (st) {
      VMCNT(3);
    } else {
      VMCNT(0);
    }
    BARR();
    load_ao<2>(sA[bufi], wm, lr, lg, af);
    if (st) {
      stageBo(t + 1, nb, 1);
      stageAo(t + 1, nb, 1);
    }
    __builtin_amdgcn_s_setprio(1);
    phase_mfma_o<2, 2>(af, bfv1, acc);
    phase_mfma_o<2, 0>(af, bfv0, acc);
    __builtin_amdgcn_s_setprio(0);
    if (st) VMCNT(2);
    BARR();
  }

#pragma unroll
  for (int i = 0; i < 4; ++i)
#pragma unroll
    for (int j = 0; j < 4; ++j)
#pragma unroll
      for (int r = 0; r < 4; ++r) {
        const int row = m0 + wm + i * 16 + lg * 4 + r;
        const int col = n0 + wn + j * 16 + lr;
        const size_t o = (size_t)row * N + col;
        Cout[o] = acc[i][j][r] + resid[o];
      }
#undef BARR
}

// -------- phase 3 (merged): q/k norm+rope AND V->V^T in one launch -------
__global__ __launch_bounds__(256) void k_post(
    const unsigned short* __restrict__ qkv, const float* __restrict__ qw,
    const float* __restrict__ kw, const float* __restrict__ cos_t,
    const float* __restrict__ sin_t, unsigned short* __restrict__ qb,
    unsigned short* __restrict__ kb, unsigned short* __restrict__ vt_out) {
  __shared__ unsigned short tile[32][33];
  if (blockIdx.x < M_) {
    const int m = blockIdx.x;
    const int b = m >> 11, s = m & (S_ - 1);
    const int w = threadIdx.x >> 6, l = threadIdx.x & 63;
    const unsigned short* row = qkv + (size_t)m * NQKV_;
    const float c = cos_t[(size_t)m * 64 + l];
    const float sn = sin_t[(size_t)m * 64 + l];
    for (int hh = w * 6; hh < w * 6 + 6; ++hh) {
      int base, type;
      unsigned short* out;
      const float* nw;
      if (hh < NH_) {
        type = 0;
        base = hh * HD_;
        out = qb + ((size_t)(b * NH_ + hh) * S_ + s) * HD_;
        nw = qw;
      } else {
        int kh = hh - NH_;
        type = 1;
        base = NH_ * HD_ + kh * HD_;
        out = kb + ((size_t)(b * NKV_ + kh) * S_ + s) * HD_;
        nw = kw;
      }
      unsigned short r1 = row[base + l];
      unsigned short r2 = row[base + 64 + l];
      float x1 = bf2f(r1), x2 = bf2f(r2);
      float ss = x1 * x1 + x2 * x2;
#pragma unroll
      for (int mk = 1; mk < 64; mk <<= 1) ss += __shfl_xor(ss, mk);
      float sc = rsqrtf(ss * (1.0f / HD_) + 1e-6f);
      float y1 = x1 * sc * nw[l];
      float y2 = x2 * sc * nw[64 + l];
      float o1 = y1 * c - y2 * sn;
      float o2 = y2 * c + y1 * sn;
      if (type == 0) {
        o1 *= QK_SCALE;
        o2 *= QK_SCALE;
      }
      out[l] = f2bf(o1);
      out[64 + l] = f2bf(o2);
    }
  } else {
    const int n = blockIdx.x - M_;
    const int bx = n & 63, by = (n >> 6) & 3, bz = n >> 8;
    const int b = bz >> 3, kh = bz & 7;
    const unsigned short* src =
        qkv + (size_t)b * S_ * NQKV_ + (NH_ + NKV_ + kh) * HD_;
    unsigned short* dst = vt_out + (size_t)bz * S_ * HD_;
    const int tx = threadIdx.x & 31, ty = threadIdx.x >> 5;
#pragma unroll
    for (int i = ty; i < 32; i += 8)
      tile[i][tx] = src[(size_t)(bx * 32 + i) * NQKV_ + by * 32 + tx];
    __syncthreads();
#pragma unroll
    for (int i = ty; i < 32; i += 8)
      dst[(size_t)(by * 32 + i) * S_ + bx * 32 + tx] = tile[tx][i];
  }
}

// ---------------- phase 4: causal GQA flash attention (paired) -----------
// R16 structure: paired q-tiles (xa, 31-xa) share one K/V staging pass;
// 8 waves/512 thr, waves 0-3 own tile-a band, 4-7 own tile-b band. Swapped
// QK^T, cvt_pk P pack, XOR swizzles, lane-local row-sum, fixed-max softmax.
// Grid x==16 strip: o_w f32->bf16 convert (hidden under attn; needed only
// by the subsequent k_gemm_ores launch).
#define MFIX 13.0f
__global__ __launch_bounds__(512, 4) void k_attn(
    const unsigned short* __restrict__ Q,   // [B*NH][S][HD] (pre-scaled)
    const unsigned short* __restrict__ K,   // [B*NKV][S][HD]
    const unsigned short* __restrict__ VT,  // [B*NKV][HD][S]
    unsigned short* __restrict__ Oa,        // [M][NH*HD]
    const float* __restrict__ o_w, unsigned short* __restrict__ owbf) {
  if (blockIdx.x == 16) {  // o_w converter strip
    const int L = blockIdx.y * 512 + threadIdx.x;
    const int stride = 32 * 512;
    const int n4 = (H_ * NH_ * HD_) / 4;
    for (int i = L; i < n4; i += stride) {
      float4 v = ((const float4*)o_w)[i];
      ushort4 o;
      o.x = f2bf(v.x);
      o.y = f2bf(v.y);
      o.z = f2bf(v.z);
      o.w = f2bf(v.w);
      ((ushort4*)owbf)[i] = o;
    }
    return;
  }
  __shared__ unsigned short kt[2][64 * 128];
  __shared__ unsigned short vt[2][128 * 64];
  __shared__ unsigned short pls[8 * 16 * 64];  // per-wave [16 q][64 kv]
  const int bh = blockIdx.y;
  const int b = bh >> 4, h = bh & 15;
  const int kvh = b * NKV_ + (h >> 1);
  const int xa = ((bh >> 4) & 1) ? (15 - blockIdx.x) : blockIdx.x;  // 0..15
  const int xb = 31 - xa;          // 16..31
  const int tid = threadIdx.x;
  const int w = tid >> 6, l = tid & 63;
  const int lr = l & 15, lg = l >> 4;
  const int wr = (w & 3) * 16;
  const int myx = (w < 4) ? xa : xb;
  const int q0m = myx * 64;

  bf16x8 qf[4];
  {
    const unsigned short* Qp = Q + ((size_t)bh * S_ + q0m + wr) * HD_;
#pragma unroll
    for (int tt = 0; tt < 4; ++tt)
      qf[tt] = *(const bf16x8*)(Qp + (size_t)lr * HD_ + tt * 32 + lg * 8);
  }
  f32x4 ao[8] = {};
  float lsum = 0.f;
  const unsigned short* Kp = K + (size_t)kvh * S_ * HD_;
  const unsigned short* Vp = VT + (size_t)kvh * HD_ * S_;
  unsigned short* pw = pls + w * 1024;
  const int psw = (lr & 7) << 1;

  auto stage = [&](int t, int bufi) {
    const int k0 = t * 64;
#pragma unroll
    for (int i = 0; i < 2; ++i) {
      const int chunk = i * 512 + tid;
      {
        const int r = chunk >> 4, p = chunk & 15;
        const int d = p ^ (r & 7);
        gload_lds16(Kp + (size_t)(k0 + r) * HD_ + d * 8,
                    (char*)kt[bufi] + (size_t)(i * 512 + w * 64) * 16);
      }
      {
        const int r = chunk >> 3, p = chunk & 7;
        const int d = p ^ (r & 7);
        gload_lds16(Vp + (size_t)r * S_ + k0 + d * 8,
                    (char*)vt[bufi] + (size_t)(i * 512 + w * 64) * 16);
      }
    }
  };

  auto process = [&](int t, int bufi, bool diag) {
    const unsigned short* ktb = kt[bufi];
    const unsigned short* vtb = vt[bufi];
    f32x4 sc[4] = {};
    __builtin_amdgcn_s_setprio(1);
#pragma unroll
    for (int j = 0; j < 4; ++j)
#pragma unroll
      for (int tt = 0; tt < 4; ++tt) {
        bf16x8 kf = *(const bf16x8*)&ktb[(j * 16 + lr) * 128 +
                                         (((tt * 4 + lg) ^ (lr & 7)) << 3)];
        sc[j] =
            __builtin_amdgcn_mfma_f32_16x16x32_bf16(kf, qf[tt], sc[j], 0, 0, 0);
      }
    __builtin_amdgcn_s_setprio(0);
    if (diag) {
      const int qg = q0m + wr + lr;
      const int kvb = t * 64 + lg * 4;
#pragma unroll
      for (int j = 0; j < 4; ++j)
#pragma unroll
        for (int r = 0; r < 4; ++r)
          if (kvb + j * 16 + r > qg) sc[j][r] = -1e30f;
    }
#pragma unroll
    for (int j = 0; j < 4; ++j) {
      float p0 = __expf(sc[j][0] - MFIX);
      float p1 = __expf(sc[j][1] - MFIX);
      float p2 = __expf(sc[j][2] - MFIX);
      float p3 = __expf(sc[j][3] - MFIX);
      lsum += (p0 + p1) + (p2 + p3);
      uint2 v;
      v.x = cvt_pk_bf16(p0, p1);
      v.y = cvt_pk_bf16(p2, p3);
      const int g = (4 * j + lg) ^ psw;
      *(uint2*)&pw[lr * 64 + g * 4] = v;
    }
    __builtin_amdgcn_s_setprio(1);
#pragma unroll
    for (int ks = 0; ks < 2; ++ks) {
      const int g0 = (8 * ks + 2 * lg) ^ psw;
      bf16x8 pf = *(const bf16x8*)&pw[lr * 64 + g0 * 4];
#pragma unroll
      for (int dj = 0; dj < 8; ++dj) {
        bf16x8 vf = *(const bf16x8*)&vtb[(dj * 16 + lr) * 64 +
                                         (((ks * 4 + lg) ^ (lr & 7)) << 3)];
        ao[dj] =
            __builtin_amdgcn_mfma_f32_16x16x32_bf16(vf, pf, ao[dj], 0, 0, 0);
      }
    }
    __builtin_amdgcn_s_setprio(0);
  };

  stage(0, 0);
  __syncthreads();
  int cur = 0;
  for (int t = 0; t <= xb; ++t) {
    if (t < xb) stage(t + 1, cur ^ 1);
    if (t <= myx) process(t, cur, t == myx);
    __syncthreads();
    cur ^= 1;
  }

  lsum += __shfl_xor(lsum, 16);
  lsum += __shfl_xor(lsum, 32);
  const float inv = 1.0f / lsum;
  const int sg = q0m + wr + lr;
  unsigned short* orow = Oa + ((size_t)b * S_ + sg) * (NH_ * HD_) + h * HD_;
#pragma unroll
  for (int dj = 0; dj < 8; ++dj) {
    ushort4 ov;
    ov.x = f2bf(ao[dj][0] * inv);
    ov.y = f2bf(ao[dj][1] * inv);
    ov.z = f2bf(ao[dj][2] * inv);
    ov.w = f2bf(ao[dj][3] * inv);
    *(ushort4*)&orow[dj * 16 + lg * 4] = ov;
  }
}

extern "C" void kernel_launch(void* const* d_in, const int* in_sizes, int n_in,
                              void* d_out, int out_size, void* d_ws,
                              size_t ws_size, hipStream_t stream) {
  const int* positions = (const int*)d_in[0];
  const float* hidden = (const float*)d_in[1];
  const float* residual = (const float*)d_in[2];
  const float* ln_w = (const float*)d_in[3];
  const float* qkv_w = (const float*)d_in[4];
  const float* o_w = (const float*)d_in[5];
  const float* q_nw = (const float*)d_in[6];
  const float* k_nw = (const float*)d_in[7];

  char* ws = (char*)d_ws;
  const size_t SZ_XN = (size_t)M_ * H_ * 2;            // 16 MiB
  const size_t SZ_QKVW = (size_t)NQKV_ * H_ * 2;       // 16 MiB
  const size_t SZ_OW = (size_t)H_ * (NH_ * HD_) * 2;   // 8 MiB
  const size_t SZ_QKV = (size_t)M_ * NQKV_ * 2;        // 32 MiB
  const size_t SZ_KB = (size_t)B_ * NKV_ * S_ * HD_ * 2;  // 8 MiB
  const size_t SZ_COS = (size_t)B_ * S_ * 64 * 4;      // 1 MiB

  unsigned short* xn = (unsigned short*)(ws);
  unsigned short* q_buf = (unsigned short*)(ws);            // reuse xn
  unsigned short* qkvw_bf = (unsigned short*)(ws + SZ_XN);
  unsigned short* k_buf = (unsigned short*)(ws + SZ_XN);    // reuse qkvw
  unsigned short* owbf = (unsigned short*)(ws + SZ_XN + SZ_QKVW);
  unsigned short* qkv_bf = (unsigned short*)(ws + SZ_XN + SZ_QKVW + SZ_OW);
  unsigned short* attn_o = qkv_bf;                          // reuse qkv
  unsigned short* vt_buf =
      (unsigned short*)(ws + SZ_XN + SZ_QKVW + SZ_OW + SZ_QKV);
  float* cos_t = (float*)(ws + SZ_XN + SZ_QKVW + SZ_OW + SZ_QKV + SZ_KB);
  float* sin_t = (float*)((char*)cos_t + SZ_COS);

  k_prep<<<M_ + 2048, 256, 0, stream>>>(positions, hidden, ln_w, qkv_w, xn,
                                        qkvw_bf, cos_t, sin_t);
  k_gemm256<<<dim3(NQKV_ / 256, M_ / 256), 512, 0, stream>>>(
      xn, qkvw_bf, qkv_bf, M_, NQKV_, H_);
  k_post<<<M_ + 4096, 256, 0, stream>>>(qkv_bf, q_nw, k_nw, cos_t, sin_t,
                                        q_buf, k_buf, vt_buf);
  k_attn<<<dim3(17, B_ * NH_), 512, 0, stream>>>(q_buf, k_buf, vt_buf, attn_o,
                                                 o_w, owbf);
  k_gemm_ores<<<dim3((NH_ * HD_) / 128, M_ / 256), 512, 0, stream>>>(
      attn_o, owbf, (float*)d_out, residual, M_, NH_ * HD_, H_);
}

// Round 19
// 204.903 us; speedup vs baseline: 1.1001x; 1.1001x over previous
//
#include <hip/hip_runtime.h>
#include <hip/hip_bf16.h>

typedef __attribute__((ext_vector_type(8))) short bf16x8;
typedef __attribute__((ext_vector_type(4))) float f32x4;

#define B_ 2
#define S_ 2048
#define H_ 2048
#define NH_ 16
#define NKV_ 8
#define HD_ 128
#define M_ (B_ * S_)                   // 4096
#define NQKV_ ((NH_ + 2 * NKV_) * HD_) // 4096
#define QK_SCALE 0.08838834764831845f  // 128^-0.5

#define VMCNT(n) asm volatile("s_waitcnt vmcnt(" #n ")" ::: "memory")

__device__ __forceinline__ unsigned short f2bf(float f) {
  unsigned int u = __float_as_uint(f);
  u += 0x7fffu + ((u >> 16) & 1u);
  return (unsigned short)(u >> 16);
}
__device__ __forceinline__ float bf2f(unsigned short h) {
  return __uint_as_float(((unsigned int)h) << 16);
}
__device__ __forceinline__ unsigned int cvt_pk_bf16(float lo, float hi) {
  unsigned int r;
  asm("v_cvt_pk_bf16_f32 %0, %1, %2" : "=v"(r) : "v"(lo), "v"(hi));
  return r;
}
__device__ __forceinline__ void gload_lds16(const void* g, void* l) {
  __builtin_amdgcn_global_load_lds(
      (const __attribute__((address_space(1))) void*)g,
      (__attribute__((address_space(3))) void*)l, 16, 0, 0);
}

// -------- phase 1 (merged): rmsnorm + weight converts + rope table --------
#define CONV_QKVW_F4 ((NQKV_ * H_) / 4)                  // 2097152
#define CONV_TOT_F4 (CONV_QKVW_F4 + (H_ * NH_ * HD_) / 4)  // 3145728
#define ROPE_N (B_ * S_ * 64)                            // 262144
__global__ __launch_bounds__(256) void k_prep(
    const int* __restrict__ positions, const float* __restrict__ hidden,
    const float* __restrict__ ln_w, const float* __restrict__ qkv_w,
    const float* __restrict__ o_w, unsigned short* __restrict__ xn,
    unsigned short* __restrict__ qkvw_bf, unsigned short* __restrict__ owbf,
    float* __restrict__ cos_t, float* __restrict__ sin_t) {
  __shared__ float red[4];
  const int t = threadIdx.x;
  if (blockIdx.x < M_) {
    const int m = blockIdx.x;
    const float4* row = (const float4*)(hidden + (size_t)m * H_);
    float4 v0 = row[t];
    float4 v1 = row[t + 256];
    float ss = v0.x * v0.x + v0.y * v0.y + v0.z * v0.z + v0.w * v0.w +
               v1.x * v1.x + v1.y * v1.y + v1.z * v1.z + v1.w * v1.w;
#pragma unroll
    for (int mk = 1; mk < 64; mk <<= 1) ss += __shfl_xor(ss, mk);
    if ((t & 63) == 0) red[t >> 6] = ss;
    __syncthreads();
    ss = red[0] + red[1] + red[2] + red[3];
    const float sc = rsqrtf(ss * (1.0f / H_) + 1e-6f);
    const float4* wv = (const float4*)ln_w;
    float4 w0 = wv[t], w1 = wv[t + 256];
    ushort4 o0, o1;
    o0.x = f2bf(v0.x * sc * w0.x);
    o0.y = f2bf(v0.y * sc * w0.y);
    o0.z = f2bf(v0.z * sc * w0.z);
    o0.w = f2bf(v0.w * sc * w0.w);
    o1.x = f2bf(v1.x * sc * w1.x);
    o1.y = f2bf(v1.y * sc * w1.y);
    o1.z = f2bf(v1.z * sc * w1.z);
    o1.w = f2bf(v1.w * sc * w1.w);
    ushort4* orow = (ushort4*)(xn + (size_t)m * H_);
    orow[t] = o0;
    orow[t + 256] = o1;
  } else {
    const int L = (blockIdx.x - M_) * 256 + t;
    const int stride = 2048 * 256;
    for (int i = L; i < CONV_TOT_F4; i += stride) {
      const float4* src4;
      ushort4* dst4;
      int idx;
      if (i < CONV_QKVW_F4) {
        src4 = (const float4*)qkv_w;
        dst4 = (ushort4*)qkvw_bf;
        idx = i;
      } else {
        src4 = (const float4*)o_w;
        dst4 = (ushort4*)owbf;
        idx = i - CONV_QKVW_F4;
      }
      float4 v = src4[idx];
      ushort4 o;
      o.x = f2bf(v.x);
      o.y = f2bf(v.y);
      o.z = f2bf(v.z);
      o.w = f2bf(v.w);
      dst4[idx] = o;
    }
    if (L < ROPE_N) {
      const int d = L & 63;
      const int bs = L >> 6;
      float pos = (float)positions[bs];
      float inv_freq = powf(10000.0f, -(float)(2 * d) * (1.0f / HD_));
      float ang = pos * inv_freq;
      cos_t[L] = cosf(ang);
      sin_t[L] = sinf(ang);
    }
  }
}

// ------ 256x256 2-phase GEMM (QKV): full-B register residency ------
template <int FMB>
__device__ __forceinline__ void load_a256(const unsigned short* sAb, int wm,
                                          int lr, int lg, bf16x8 (&af)[2][4]) {
#pragma unroll
  for (int kk = 0; kk < 2; ++kk) {
    const int pc = kk * 4 + lg;
#pragma unroll
    for (int i = 0; i < 4; ++i) {
      const int R = wm + (FMB + i) * 16 + lr;
      const int idx = ((R >> 6) & 1) * 8192 +
                      ((((R >> 7) << 6) | (R & 63)) << 6) +
                      ((pc ^ (R & 7)) << 3);
      af[kk][i] = *(const bf16x8*)&sAb[idx];
    }
  }
}
template <int FNB>
__device__ __forceinline__ void load_b256(const unsigned short* sBb, int wn,
                                          int lr, int lg, bf16x8 (&bfv)[2][2]) {
#pragma unroll
  for (int kk = 0; kk < 2; ++kk) {
    const int pc = kk * 4 + lg;
#pragma unroll
    for (int j = 0; j < 2; ++j) {
      const int R = wn + (FNB + j) * 16 + lr;
      const int idx = ((R >> 5) & 1) * 8192 +
                      ((((R >> 6) << 5) | (R & 31)) << 6) +
                      ((pc ^ (R & 7)) << 3);
      bfv[kk][j] = *(const bf16x8*)&sBb[idx];
    }
  }
}

template <int FMB, int FNB>
__device__ __forceinline__ void phase_mfma(const bf16x8 (&af)[2][4],
                                           const bf16x8 (&bfv)[2][2],
                                           f32x4 (&acc)[8][4]) {
#pragma unroll
  for (int kk = 0; kk < 2; ++kk)
#pragma unroll
    for (int i = 0; i < 4; ++i)
#pragma unroll
      for (int j = 0; j < 2; ++j)
        acc[FMB + i][FNB + j] = __builtin_amdgcn_mfma_f32_16x16x32_bf16(
            af[kk][i], bfv[kk][j], acc[FMB + i][FNB + j], 0, 0, 0);
}

__global__ __launch_bounds__(512, 2) void k_gemm256(
    const unsigned short* __restrict__ A, const unsigned short* __restrict__ Bt,
    unsigned short* __restrict__ C, int M, int N, int K) {
  __shared__ unsigned short sA[2][256 * 64];
  __shared__ unsigned short sB[2][256 * 64];
  const int tid = threadIdx.x;
  const int w = tid >> 6;
  const int l = tid & 63;
  const int lr = l & 15, lg = l >> 4;
  const int gx = gridDim.x;
  const int lin = blockIdx.y * gx + blockIdx.x;
  const int cpx = (gx * gridDim.y) >> 3;
  const int swz = (lin & 7) * cpx + (lin >> 3);
  const int m0 = (swz / gx) * 256, n0 = (swz % gx) * 256;
  const int wm = (w >> 2) * 128, wn = (w & 3) * 64;
  f32x4 acc[8][4] = {};

  auto stageA = [&](int t, int bufi, int h) {
    const int k0 = t * 64;
#pragma unroll
    for (int i = 0; i < 2; ++i) {
      const int L = i * 512 + tid;
      const int r = L >> 3;
      const int R = ((r >> 6) << 7) | (h << 6) | (r & 63);
      const int d = (L & 7) ^ (r & 7);
      gload_lds16(A + (size_t)(m0 + R) * K + k0 + d * 8,
                  (char*)sA[bufi] + h * 16384 +
                      (size_t)(i * 512 + w * 64) * 16);
    }
  };
  auto stageB = [&](int t, int bufi, int h) {
    const int k0 = t * 64;
#pragma unroll
    for (int i = 0; i < 2; ++i) {
      const int L = i * 512 + tid;
      const int r = L >> 3;
      const int R = ((r >> 5) << 6) | (h << 5) | (r & 31);
      const int d = (L & 7) ^ (r & 7);
      gload_lds16(Bt + (size_t)(n0 + R) * K + k0 + d * 8,
                  (char*)sB[bufi] + h * 16384 +
                      (size_t)(i * 512 + w * 64) * 16);
    }
  };

#define BARR()                          \
  __builtin_amdgcn_s_barrier();         \
  __builtin_amdgcn_sched_barrier(0)

  stageA(0, 0, 0);
  stageB(0, 0, 0);
  stageB(0, 0, 1);
  stageA(0, 0, 1);
  VMCNT(2);
  BARR();

  bf16x8 af[2][4];
  bf16x8 bfv0[2][2];
  bf16x8 bfv1[2][2];
  const int NT = K >> 6;
  for (int t = 0; t < NT; ++t) {
    const int bufi = t & 1;
    const int nb = bufi ^ 1;
    const bool st = (t + 1 < NT);
    load_a256<0>(sA[bufi], wm, lr, lg, af);
    load_b256<0>(sB[bufi], wn, lr, lg, bfv0);
    load_b256<2>(sB[bufi], wn, lr, lg, bfv1);
    if (st) {
      stageA(t + 1, nb, 0);
      stageB(t + 1, nb, 0);
    }
    __builtin_amdgcn_s_setprio(1);
    phase_mfma<0, 0>(af, bfv0, acc);
    phase_mfma<0, 2>(af, bfv1, acc);
    __builtin_amdgcn_s_setprio(0);
    if (st) {
      VMCNT(4);
    } else {
      VMCNT(0);
    }
    BARR();
    load_a256<4>(sA[bufi], wm, lr, lg, af);
    if (st) {
      stageB(t + 1, nb, 1);
      stageA(t + 1, nb, 1);
    }
    __builtin_amdgcn_s_setprio(1);
    phase_mfma<4, 2>(af, bfv1, acc);
    phase_mfma<4, 0>(af, bfv0, acc);
    __builtin_amdgcn_s_setprio(0);
    if (st) VMCNT(2);
    BARR();
  }

#pragma unroll
  for (int fm = 0; fm < 8; ++fm)
#pragma unroll
    for (int fn = 0; fn < 4; ++fn)
#pragma unroll
      for (int r = 0; r < 4; ++r) {
        const int row = m0 + wm + fm * 16 + lg * 4 + r;
        const int col = n0 + wn + fn * 16 + lr;
        C[(size_t)row * N + col] = f2bf(acc[fm][fn][r]);
      }
#undef BARR
}

// ------ 256x128 2-phase GEMM (O-proj: f32 out += resid) ------
template <int FMB>
__device__ __forceinline__ void load_ao(const unsigned short* sAb, int wm,
                                        int lr, int lg, bf16x8 (&af)[2][2]) {
#pragma unroll
  for (int kk = 0; kk < 2; ++kk) {
    const int pc = kk * 4 + lg;
#pragma unroll
    for (int i = 0; i < 2; ++i) {
      const int R = wm + (FMB + i) * 16 + lr;
      const int idx = ((R >> 5) & 1) * 8192 +
                      ((((R >> 6) << 5) | (R & 31)) << 6) +
                      ((pc ^ (R & 7)) << 3);
      af[kk][i] = *(const bf16x8*)&sAb[idx];
    }
  }
}
template <int FNB>
__device__ __forceinline__ void load_bo(const unsigned short* sBb, int wn,
                                        int lr, int lg, bf16x8 (&bfv)[2][2]) {
#pragma unroll
  for (int kk = 0; kk < 2; ++kk) {
    const int pc = kk * 4 + lg;
#pragma unroll
    for (int j = 0; j < 2; ++j) {
      const int R = wn + (FNB + j) * 16 + lr;
      const int idx = ((R >> 5) & 1) * 4096 +
                      ((((R >> 6) << 5) | (R & 31)) << 6) +
                      ((pc ^ (R & 7)) << 3);
      bfv[kk][j] = *(const bf16x8*)&sBb[idx];
    }
  }
}

template <int FMB, int FNB>
__device__ __forceinline__ void phase_mfma_o(const bf16x8 (&af)[2][2],
                                             const bf16x8 (&bfv)[2][2],
                                             f32x4 (&acc)[4][4]) {
#pragma unroll
  for (int kk = 0; kk < 2; ++kk)
#pragma unroll
    for (int i = 0; i < 2; ++i)
#pragma unroll
      for (int j = 0; j < 2; ++j)
        acc[FMB + i][FNB + j] = __builtin_amdgcn_mfma_f32_16x16x32_bf16(
            af[kk][i], bfv[kk][j], acc[FMB + i][FNB + j], 0, 0, 0);
}

__global__ __launch_bounds__(512, 1) void k_gemm_ores(
    const unsigned short* __restrict__ A, const unsigned short* __restrict__ Bt,
    float* __restrict__ Cout, const float* __restrict__ resid, int M, int N,
    int K) {
  __shared__ unsigned short sA[2][256 * 64];
  __shared__ unsigned short sB[2][128 * 64];
  const int tid = threadIdx.x;
  const int w = tid >> 6;
  const int l = tid & 63;
  const int lr = l & 15, lg = l >> 4;
  const int gx = gridDim.x;
  const int lin = blockIdx.y * gx + blockIdx.x;
  const int cpx = (gx * gridDim.y) >> 3;
  const int swz = (lin & 7) * cpx + (lin >> 3);
  const int m0 = (swz / gx) * 256, n0 = (swz % gx) * 128;
  const int wm = (w >> 1) * 64, wn = (w & 1) * 64;
  f32x4 acc[4][4] = {};

  auto stageAo = [&](int t, int bufi, int h) {
    const int k0 = t * 64;
#pragma unroll
    for (int i = 0; i < 2; ++i) {
      const int L = i * 512 + tid;
      const int r = L >> 3;
      const int R = ((r >> 5) << 6) | (h << 5) | (r & 31);
      const int d = (L & 7) ^ (r & 7);
      gload_lds16(A + (size_t)(m0 + R) * K + k0 + d * 8,
                  (char*)sA[bufi] + h * 16384 +
                      (size_t)(i * 512 + w * 64) * 16);
    }
  };
  auto stageBo = [&](int t, int bufi, int h) {
    const int k0 = t * 64;
    const int L = tid;
    const int r = L >> 3;
    const int R = ((r >> 5) << 6) | (h << 5) | (r & 31);
    const int d = (L & 7) ^ (r & 7);
    gload_lds16(Bt + (size_t)(n0 + R) * K + k0 + d * 8,
                (char*)sB[bufi] + h * 8192 + (size_t)(w * 64) * 16);
  };

#define BARR()                          \
  __builtin_amdgcn_s_barrier();         \
  __builtin_amdgcn_sched_barrier(0)

  stageAo(0, 0, 0);
  stageBo(0, 0, 0);
  stageBo(0, 0, 1);
  stageAo(0, 0, 1);
  VMCNT(2);
  BARR();

  bf16x8 af[2][2];
  bf16x8 bfv0[2][2];
  bf16x8 bfv1[2][2];
  const int NT = K >> 6;
  for (int t = 0; t < NT; ++t) {
    const int bufi = t & 1;
    const int nb = bufi ^ 1;
    const bool st = (t + 1 < NT);
    load_ao<0>(sA[bufi], wm, lr, lg, af);
    load_bo<0>(sB[bufi], wn, lr, lg, bfv0);
    load_bo<2>(sB[bufi], wn, lr, lg, bfv1);
    if (st) {
      stageAo(t + 1, nb, 0);
      stageBo(t + 1, nb, 0);
    }
    __builtin_amdgcn_s_setprio(1);
    phase_mfma_o<0, 0>(af, bfv0, acc);
    phase_mfma_o<0, 2>(af, bfv1, acc);
    __builtin_amdgcn_s_setprio(0);
    if (st) {
      VMCNT(3);
    } else {
      VMCNT(0);
    }
    BARR();
    load_ao<2>(sA[bufi], wm, lr, lg, af);
    if (st) {
      stageBo(t + 1, nb, 1);
      stageAo(t + 1, nb, 1);
    }
    __builtin_amdgcn_s_setprio(1);
    phase_mfma_o<2, 2>(af, bfv1, acc);
    phase_mfma_o<2, 0>(af, bfv0, acc);
    __builtin_amdgcn_s_setprio(0);
    if (st) VMCNT(2);
    BARR();
  }

#pragma unroll
  for (int i = 0; i < 4; ++i)
#pragma unroll
    for (int j = 0; j < 4; ++j)
#pragma unroll
      for (int r = 0; r < 4; ++r) {
        const int row = m0 + wm + i * 16 + lg * 4 + r;
        const int col = n0 + wn + j * 16 + lr;
        const size_t o = (size_t)row * N + col;
        Cout[o] = acc[i][j][r] + resid[o];
      }
#undef BARR
}

// -------- phase 3 (merged): q/k norm+rope AND V->V^T in one launch -------
__global__ __launch_bounds__(256) void k_post(
    const unsigned short* __restrict__ qkv, const float* __restrict__ qw,
    const float* __restrict__ kw, const float* __restrict__ cos_t,
    const float* __restrict__ sin_t, unsigned short* __restrict__ qb,
    unsigned short* __restrict__ kb, unsigned short* __restrict__ vt_out) {
  __shared__ unsigned short tile[32][33];
  if (blockIdx.x < M_) {
    const int m = blockIdx.x;
    const int b = m >> 11, s = m & (S_ - 1);
    const int w = threadIdx.x >> 6, l = threadIdx.x & 63;
    const unsigned short* row = qkv + (size_t)m * NQKV_;
    const float c = cos_t[(size_t)m * 64 + l];
    const float sn = sin_t[(size_t)m * 64 + l];
    for (int hh = w * 6; hh < w * 6 + 6; ++hh) {
      int base, type;
      unsigned short* out;
      const float* nw;
      if (hh < NH_) {
        type = 0;
        base = hh * HD_;
        out = qb + ((size_t)(b * NH_ + hh) * S_ + s) * HD_;
        nw = qw;
      } else {
        int kh = hh - NH_;
        type = 1;
        base = NH_ * HD_ + kh * HD_;
        out = kb + ((size_t)(b * NKV_ + kh) * S_ + s) * HD_;
        nw = kw;
      }
      unsigned short r1 = row[base + l];
      unsigned short r2 = row[base + 64 + l];
      float x1 = bf2f(r1), x2 = bf2f(r2);
      float ss = x1 * x1 + x2 * x2;
#pragma unroll
      for (int mk = 1; mk < 64; mk <<= 1) ss += __shfl_xor(ss, mk);
      float sc = rsqrtf(ss * (1.0f / HD_) + 1e-6f);
      float y1 = x1 * sc * nw[l];
      float y2 = x2 * sc * nw[64 + l];
      float o1 = y1 * c - y2 * sn;
      float o2 = y2 * c + y1 * sn;
      if (type == 0) {
        o1 *= QK_SCALE;
        o2 *= QK_SCALE;
      }
      out[l] = f2bf(o1);
      out[64 + l] = f2bf(o2);
    }
  } else {
    const int n = blockIdx.x - M_;
    const int bx = n & 63, by = (n >> 6) & 3, bz = n >> 8;
    const int b = bz >> 3, kh = bz & 7;
    const unsigned short* src =
        qkv + (size_t)b * S_ * NQKV_ + (NH_ + NKV_ + kh) * HD_;
    unsigned short* dst = vt_out + (size_t)bz * S_ * HD_;
    const int tx = threadIdx.x & 31, ty = threadIdx.x >> 5;
#pragma unroll
    for (int i = ty; i < 32; i += 8)
      tile[i][tx] = src[(size_t)(bx * 32 + i) * NQKV_ + by * 32 + tx];
    __syncthreads();
#pragma unroll
    for (int i = ty; i < 32; i += 8)
      dst[(size_t)(by * 32 + i) * S_ + bx * 32 + tx] = tile[tx][i];
  }
}

// ---------------- phase 4: causal GQA flash attention --------------------
// Paired q-tiles (xa, 31-xa) share one K/V staging pass; 8 waves/512 thr.
// Grid exactly 16x32 = 512 blocks = 2/CU slots (do NOT exceed). Swapped
// QK^T, cvt_pk P pack, XOR swizzles, lane-local row-sum, fixed-max softmax.
#define MFIX 13.0f
__global__ __launch_bounds__(512, 4) void k_attn(
    const unsigned short* __restrict__ Q,   // [B*NH][S][HD] (pre-scaled)
    const unsigned short* __restrict__ K,   // [B*NKV][S][HD]
    const unsigned short* __restrict__ VT,  // [B*NKV][HD][S]
    unsigned short* __restrict__ Oa) {      // [M][NH*HD]
  __shared__ unsigned short kt[2][64 * 128];
  __shared__ unsigned short vt[2][128 * 64];
  __shared__ unsigned short pls[8 * 16 * 64];  // per-wave [16 q][64 kv]
  const int bh = blockIdx.y;
  const int b = bh >> 4, h = bh & 15;
  const int kvh = b * NKV_ + (h >> 1);
  const int xa = ((bh >> 4) & 1) ? (15 - blockIdx.x) : blockIdx.x;  // 0..15
  const int xb = 31 - xa;          // 16..31
  const int tid = threadIdx.x;
  const int w = tid >> 6, l = tid & 63;
  const int lr = l & 15, lg = l >> 4;
  const int wr = (w & 3) * 16;
  const int myx = (w < 4) ? xa : xb;
  const int q0m = myx * 64;

  bf16x8 qf[4];
  {
    const unsigned short* Qp = Q + ((size_t)bh * S_ + q0m + wr) * HD_;
#pragma unroll
    for (int tt = 0; tt < 4; ++tt)
      qf[tt] = *(const bf16x8*)(Qp + (size_t)lr * HD_ + tt * 32 + lg * 8);
  }
  f32x4 ao[8] = {};
  float lsum = 0.f;
  const unsigned short* Kp = K + (size_t)kvh * S_ * HD_;
  const unsigned short* Vp = VT + (size_t)kvh * HD_ * S_;
  unsigned short* pw = pls + w * 1024;
  const int psw = (lr & 7) << 1;

  auto stage = [&](int t, int bufi) {
    const int k0 = t * 64;
#pragma unroll
    for (int i = 0; i < 2; ++i) {
      const int chunk = i * 512 + tid;
      {
        const int r = chunk >> 4, p = chunk & 15;
        const int d = p ^ (r & 7);
        gload_lds16(Kp + (size_t)(k0 + r) * HD_ + d * 8,
                    (char*)kt[bufi] + (size_t)(i * 512 + w * 64) * 16);
      }
      {
        const int r = chunk >> 3, p = chunk & 7;
        const int d = p ^ (r & 7);
        gload_lds16(Vp + (size_t)r * S_ + k0 + d * 8,
                    (char*)vt[bufi] + (size_t)(i * 512 + w * 64) * 16);
      }
    }
  };

  auto process = [&](int t, int bufi, bool diag) {
    const unsigned short* ktb = kt[bufi];
    const unsigned short* vtb = vt[bufi];
    f32x4 sc[4] = {};
    __builtin_amdgcn_s_setprio(1);
#pragma unroll
    for (int j = 0; j < 4; ++j)
#pragma unroll
      for (int tt = 0; tt < 4; ++tt) {
        bf16x8 kf = *(const bf16x8*)&ktb[(j * 16 + lr) * 128 +
                                         (((tt * 4 + lg) ^ (lr & 7)) << 3)];
        sc[j] =
            __builtin_amdgcn_mfma_f32_16x16x32_bf16(kf, qf[tt], sc[j], 0, 0, 0);
      }
    __builtin_amdgcn_s_setprio(0);
    if (diag) {
      const int qg = q0m + wr + lr;
      const int kvb = t * 64 + lg * 4;
#pragma unroll
      for (int j = 0; j < 4; ++j)
#pragma unroll
        for (int r = 0; r < 4; ++r)
          if (kvb + j * 16 + r > qg) sc[j][r] = -1e30f;
    }
#pragma unroll
    for (int j = 0; j < 4; ++j) {
      float p0 = __expf(sc[j][0] - MFIX);
      float p1 = __expf(sc[j][1] - MFIX);
      float p2 = __expf(sc[j][2] - MFIX);
      float p3 = __expf(sc[j][3] - MFIX);
      lsum += (p0 + p1) + (p2 + p3);
      uint2 v;
      v.x = cvt_pk_bf16(p0, p1);
      v.y = cvt_pk_bf16(p2, p3);
      const int g = (4 * j + lg) ^ psw;
      *(uint2*)&pw[lr * 64 + g * 4] = v;
    }
    __builtin_amdgcn_s_setprio(1);
#pragma unroll
    for (int ks = 0; ks < 2; ++ks) {
      const int g0 = (8 * ks + 2 * lg) ^ psw;
      bf16x8 pf = *(const bf16x8*)&pw[lr * 64 + g0 * 4];
#pragma unroll
      for (int dj = 0; dj < 8; ++dj) {
        bf16x8 vf = *(const bf16x8*)&vtb[(dj * 16 + lr) * 64 +
                                         (((ks * 4 + lg) ^ (lr & 7)) << 3)];
        ao[dj] =
            __builtin_amdgcn_mfma_f32_16x16x32_bf16(vf, pf, ao[dj], 0, 0, 0);
      }
    }
    __builtin_amdgcn_s_setprio(0);
  };

  stage(0, 0);
  __syncthreads();
  int cur = 0;
  for (int t = 0; t <= xb; ++t) {
    if (t < xb) stage(t + 1, cur ^ 1);
    if (t <= myx) process(t, cur, t == myx);
    __syncthreads();
    cur ^= 1;
  }

  lsum += __shfl_xor(lsum, 16);
  lsum += __shfl_xor(lsum, 32);
  const float inv = 1.0f / lsum;
  const int sg = q0m + wr + lr;
  unsigned short* orow = Oa + ((size_t)b * S_ + sg) * (NH_ * HD_) + h * HD_;
#pragma unroll
  for (int dj = 0; dj < 8; ++dj) {
    ushort4 ov;
    ov.x = f2bf(ao[dj][0] * inv);
    ov.y = f2bf(ao[dj][1] * inv);
    ov.z = f2bf(ao[dj][2] * inv);
    ov.w = f2bf(ao[dj][3] * inv);
    *(ushort4*)&orow[dj * 16 + lg * 4] = ov;
  }
}

extern "C" void kernel_launch(void* const* d_in, const int* in_sizes, int n_in,
                              void* d_out, int out_size, void* d_ws,
                              size_t ws_size, hipStream_t stream) {
  const int* positions = (const int*)d_in[0];
  const float* hidden = (const float*)d_in[1];
  const float* residual = (const float*)d_in[2];
  const float* ln_w = (const float*)d_in[3];
  const float* qkv_w = (const float*)d_in[4];
  const float* o_w = (const float*)d_in[5];
  const float* q_nw = (const float*)d_in[6];
  const float* k_nw = (const float*)d_in[7];

  char* ws = (char*)d_ws;
  const size_t SZ_XN = (size_t)M_ * H_ * 2;            // 16 MiB
  const size_t SZ_QKVW = (size_t)NQKV_ * H_ * 2;       // 16 MiB
  const size_t SZ_OW = (size_t)H_ * (NH_ * HD_) * 2;   // 8 MiB
  const size_t SZ_QKV = (size_t)M_ * NQKV_ * 2;        // 32 MiB
  const size_t SZ_KB = (size_t)B_ * NKV_ * S_ * HD_ * 2;  // 8 MiB
  const size_t SZ_COS = (size_t)B_ * S_ * 64 * 4;      // 1 MiB

  unsigned short* xn = (unsigned short*)(ws);
  unsigned short* q_buf = (unsigned short*)(ws);            // reuse xn
  unsigned short* qkvw_bf = (unsigned short*)(ws + SZ_XN);
  unsigned short* k_buf = (unsigned short*)(ws + SZ_XN);    // reuse qkvw
  unsigned short* owbf = (unsigned short*)(ws + SZ_XN + SZ_QKVW);
  unsigned short* qkv_bf = (unsigned short*)(ws + SZ_XN + SZ_QKVW + SZ_OW);
  unsigned short* attn_o = qkv_bf;                          // reuse qkv
  unsigned short* vt_buf =
      (unsigned short*)(ws + SZ_XN + SZ_QKVW + SZ_OW + SZ_QKV);
  float* cos_t = (float*)(ws + SZ_XN + SZ_QKVW + SZ_OW + SZ_QKV + SZ_KB);
  float* sin_t = (float*)((char*)cos_t + SZ_COS);

  k_prep<<<M_ + 2048, 256, 0, stream>>>(positions, hidden, ln_w, qkv_w, o_w,
                                        xn, qkvw_bf, owbf, cos_t, sin_t);
  k_gemm256<<<dim3(NQKV_ / 256, M_ / 256), 512, 0, stream>>>(
      xn, qkvw_bf, qkv_bf, M_, NQKV_, H_);
  k_post<<<M_ + 4096, 256, 0, stream>>>(qkv_bf, q_nw, k_nw, cos_t, sin_t,
                                        q_buf, k_buf, vt_buf);
  k_attn<<<dim3(16, B_ * NH_), 512, 0, stream>>>(q_buf, k_buf, vt_buf, attn_o);
  k_gemm_ores<<<dim3((NH_ * HD_) / 128, M_ / 256), 512, 0, stream>>>(
      attn_o, owbf, (float*)d_out, residual, M_, NH_ * HD_, H_);
}

// Round 20
// 203.661 us; speedup vs baseline: 1.1068x; 1.0061x over previous
//
#include <hip/hip_runtime.h>
#include <hip/hip_bf16.h>

typedef __attribute__((ext_vector_type(8))) short bf16x8;
typedef __attribute__((ext_vector_type(4))) float f32x4;

#define B_ 2
#define S_ 2048
#define H_ 2048
#define NH_ 16
#define NKV_ 8
#define HD_ 128
#define M_ (B_ * S_)                   // 4096
#define NQKV_ ((NH_ + 2 * NKV_) * HD_) // 4096
#define QK_SCALE 0.08838834764831845f  // 128^-0.5

#define VMCNT(n) asm volatile("s_waitcnt vmcnt(" #n ")" ::: "memory")

__device__ __forceinline__ unsigned short f2bf(float f) {
  unsigned int u = __float_as_uint(f);
  u += 0x7fffu + ((u >> 16) & 1u);
  return (unsigned short)(u >> 16);
}
__device__ __forceinline__ float bf2f(unsigned short h) {
  return __uint_as_float(((unsigned int)h) << 16);
}
__device__ __forceinline__ unsigned int cvt_pk_bf16(float lo, float hi) {
  unsigned int r;
  asm("v_cvt_pk_bf16_f32 %0, %1, %2" : "=v"(r) : "v"(lo), "v"(hi));
  return r;
}
__device__ __forceinline__ void gload_lds16(const void* g, void* l) {
  __builtin_amdgcn_global_load_lds(
      (const __attribute__((address_space(1))) void*)g,
      (__attribute__((address_space(3))) void*)l, 16, 0, 0);
}

// -------- phase 1 (merged): rmsnorm + weight converts + rope table --------
#define CONV_QKVW_F4 ((NQKV_ * H_) / 4)                  // 2097152
#define CONV_TOT_F4 (CONV_QKVW_F4 + (H_ * NH_ * HD_) / 4)  // 3145728
#define ROPE_N (B_ * S_ * 64)                            // 262144
__global__ __launch_bounds__(256) void k_prep(
    const int* __restrict__ positions, const float* __restrict__ hidden,
    const float* __restrict__ ln_w, const float* __restrict__ qkv_w,
    const float* __restrict__ o_w, unsigned short* __restrict__ xn,
    unsigned short* __restrict__ qkvw_bf, unsigned short* __restrict__ owbf,
    float* __restrict__ cos_t, float* __restrict__ sin_t) {
  __shared__ float red[4];
  const int t = threadIdx.x;
  if (blockIdx.x < M_) {
    const int m = blockIdx.x;
    const float4* row = (const float4*)(hidden + (size_t)m * H_);
    float4 v0 = row[t];
    float4 v1 = row[t + 256];
    float ss = v0.x * v0.x + v0.y * v0.y + v0.z * v0.z + v0.w * v0.w +
               v1.x * v1.x + v1.y * v1.y + v1.z * v1.z + v1.w * v1.w;
#pragma unroll
    for (int mk = 1; mk < 64; mk <<= 1) ss += __shfl_xor(ss, mk);
    if ((t & 63) == 0) red[t >> 6] = ss;
    __syncthreads();
    ss = red[0] + red[1] + red[2] + red[3];
    const float sc = rsqrtf(ss * (1.0f / H_) + 1e-6f);
    const float4* wv = (const float4*)ln_w;
    float4 w0 = wv[t], w1 = wv[t + 256];
    ushort4 o0, o1;
    o0.x = f2bf(v0.x * sc * w0.x);
    o0.y = f2bf(v0.y * sc * w0.y);
    o0.z = f2bf(v0.z * sc * w0.z);
    o0.w = f2bf(v0.w * sc * w0.w);
    o1.x = f2bf(v1.x * sc * w1.x);
    o1.y = f2bf(v1.y * sc * w1.y);
    o1.z = f2bf(v1.z * sc * w1.z);
    o1.w = f2bf(v1.w * sc * w1.w);
    ushort4* orow = (ushort4*)(xn + (size_t)m * H_);
    orow[t] = o0;
    orow[t + 256] = o1;
  } else {
    const int L = (blockIdx.x - M_) * 256 + t;
    const int stride = 2048 * 256;
    for (int i = L; i < CONV_TOT_F4; i += stride) {
      const float4* src4;
      ushort4* dst4;
      int idx;
      if (i < CONV_QKVW_F4) {
        src4 = (const float4*)qkv_w;
        dst4 = (ushort4*)qkvw_bf;
        idx = i;
      } else {
        src4 = (const float4*)o_w;
        dst4 = (ushort4*)owbf;
        idx = i - CONV_QKVW_F4;
      }
      float4 v = src4[idx];
      ushort4 o;
      o.x = f2bf(v.x);
      o.y = f2bf(v.y);
      o.z = f2bf(v.z);
      o.w = f2bf(v.w);
      dst4[idx] = o;
    }
    if (L < ROPE_N) {
      const int d = L & 63;
      const int bs = L >> 6;
      float pos = (float)positions[bs];
      float inv_freq = powf(10000.0f, -(float)(2 * d) * (1.0f / HD_));
      float ang = pos * inv_freq;
      cos_t[L] = cosf(ang);
      sin_t[L] = sinf(ang);
    }
  }
}

// ------ 256x256 4-phase GEMM (QKV): Gray quadrants, deep counted vmcnt ----
// Phase = [VMCNT -> barrier -> fresh ds_reads -> stage 1 half-tile -> 16
// MFMA]. Quadrants (0,0)->(0,2)->(4,2)->(4,0); A reloaded per half, both B
// sets held. Stage order = first-use order [A0,B0,B1,A1] -> steady waits
// VMCNT(4) at ph1/ph2/ph3, none ph4 (~3 phases of flight per half-tile);
// epilogue 4/2/0/-. ph4 reads nothing fresh -> no barrier (overwrite safety:
// last LDS reads of a buffer are ph3's, consumed before any wave passes the
// next iteration's ph1 barrier, which precedes the overwriting stage).
template <int FMB>
__device__ __forceinline__ void load_a256(const unsigned short* sAb, int wm,
                                          int lr, int lg, bf16x8 (&af)[2][4]) {
#pragma unroll
  for (int kk = 0; kk < 2; ++kk) {
    const int pc = kk * 4 + lg;
#pragma unroll
    for (int i = 0; i < 4; ++i) {
      const int R = wm + (FMB + i) * 16 + lr;
      const int idx = ((R >> 6) & 1) * 8192 +
                      ((((R >> 7) << 6) | (R & 63)) << 6) +
                      ((pc ^ (R & 7)) << 3);
      af[kk][i] = *(const bf16x8*)&sAb[idx];
    }
  }
}
template <int FNB>
__device__ __forceinline__ void load_b256(const unsigned short* sBb, int wn,
                                          int lr, int lg, bf16x8 (&bfv)[2][2]) {
#pragma unroll
  for (int kk = 0; kk < 2; ++kk) {
    const int pc = kk * 4 + lg;
#pragma unroll
    for (int j = 0; j < 2; ++j) {
      const int R = wn + (FNB + j) * 16 + lr;
      const int idx = ((R >> 5) & 1) * 8192 +
                      ((((R >> 6) << 5) | (R & 31)) << 6) +
                      ((pc ^ (R & 7)) << 3);
      bfv[kk][j] = *(const bf16x8*)&sBb[idx];
    }
  }
}

template <int FMB, int FNB>
__device__ __forceinline__ void phase_mfma(const bf16x8 (&af)[2][4],
                                           const bf16x8 (&bfv)[2][2],
                                           f32x4 (&acc)[8][4]) {
#pragma unroll
  for (int kk = 0; kk < 2; ++kk)
#pragma unroll
    for (int i = 0; i < 4; ++i)
#pragma unroll
      for (int j = 0; j < 2; ++j)
        acc[FMB + i][FNB + j] = __builtin_amdgcn_mfma_f32_16x16x32_bf16(
            af[kk][i], bfv[kk][j], acc[FMB + i][FNB + j], 0, 0, 0);
}

__global__ __launch_bounds__(512, 2) void k_gemm256(
    const unsigned short* __restrict__ A, const unsigned short* __restrict__ Bt,
    unsigned short* __restrict__ C, int M, int N, int K) {
  __shared__ unsigned short sA[2][256 * 64];
  __shared__ unsigned short sB[2][256 * 64];
  const int tid = threadIdx.x;
  const int w = tid >> 6;
  const int l = tid & 63;
  const int lr = l & 15, lg = l >> 4;
  const int gx = gridDim.x;
  const int lin = blockIdx.y * gx + blockIdx.x;
  const int cpx = (gx * gridDim.y) >> 3;
  const int swz = (lin & 7) * cpx + (lin >> 3);
  const int m0 = (swz / gx) * 256, n0 = (swz % gx) * 256;
  const int wm = (w >> 2) * 128, wn = (w & 3) * 64;
  f32x4 acc[8][4] = {};

  auto stageA = [&](int t, int bufi, int h) {
    const int k0 = t * 64;
#pragma unroll
    for (int i = 0; i < 2; ++i) {
      const int L = i * 512 + tid;
      const int r = L >> 3;
      const int R = ((r >> 6) << 7) | (h << 6) | (r & 63);
      const int d = (L & 7) ^ (r & 7);
      gload_lds16(A + (size_t)(m0 + R) * K + k0 + d * 8,
                  (char*)sA[bufi] + h * 16384 +
                      (size_t)(i * 512 + w * 64) * 16);
    }
  };
  auto stageB = [&](int t, int bufi, int h) {
    const int k0 = t * 64;
#pragma unroll
    for (int i = 0; i < 2; ++i) {
      const int L = i * 512 + tid;
      const int r = L >> 3;
      const int R = ((r >> 5) << 6) | (h << 5) | (r & 31);
      const int d = (L & 7) ^ (r & 7);
      gload_lds16(Bt + (size_t)(n0 + R) * K + k0 + d * 8,
                  (char*)sB[bufi] + h * 16384 +
                      (size_t)(i * 512 + w * 64) * 16);
    }
  };

#define BARR()                          \
  __builtin_amdgcn_s_barrier();         \
  __builtin_amdgcn_sched_barrier(0)

  // prologue: stage tile0 in first-use order A0,B0,B1,A1
  stageA(0, 0, 0);
  stageB(0, 0, 0);
  stageB(0, 0, 1);
  stageA(0, 0, 1);

  bf16x8 af[2][4];
  bf16x8 bfv0[2][2];
  bf16x8 bfv1[2][2];
  const int NT = K >> 6;
  for (int t = 0; t < NT; ++t) {
    const int bufi = t & 1;
    const int nb = bufi ^ 1;
    const bool st = (t + 1 < NT);
    // ph1: quadrant (0,0); fresh A0,B0; stage A0(t+1)
    VMCNT(4);  // A0,B0(t) landed (oldest 4 of 8 outstanding)
    BARR();
    load_a256<0>(sA[bufi], wm, lr, lg, af);
    load_b256<0>(sB[bufi], wn, lr, lg, bfv0);
    if (st) stageA(t + 1, nb, 0);
    __builtin_amdgcn_s_setprio(1);
    phase_mfma<0, 0>(af, bfv0, acc);
    __builtin_amdgcn_s_setprio(0);
    // ph2: quadrant (0,2); fresh B1 (A0 held); stage B0(t+1)
    if (st) {
      VMCNT(4);  // B1(t) landed; leaves A1(t),A0(t+1)
    } else {
      VMCNT(2);
    }
    BARR();
    load_b256<2>(sB[bufi], wn, lr, lg, bfv1);
    if (st) stageB(t + 1, nb, 0);
    __builtin_amdgcn_s_setprio(1);
    phase_mfma<0, 2>(af, bfv1, acc);
    __builtin_amdgcn_s_setprio(0);
    // ph3: quadrant (4,2); fresh A1 (B1 held); stage B1(t+1)
    if (st) {
      VMCNT(4);  // A1(t) landed; leaves A0,B0(t+1)
    } else {
      VMCNT(0);
    }
    BARR();
    load_a256<4>(sA[bufi], wm, lr, lg, af);
    if (st) stageB(t + 1, nb, 1);
    __builtin_amdgcn_s_setprio(1);
    phase_mfma<4, 2>(af, bfv1, acc);
    __builtin_amdgcn_s_setprio(0);
    // ph4: quadrant (4,0); nothing fresh (A1,B0 held); stage A1(t+1)
    if (st) stageA(t + 1, nb, 1);
    __builtin_amdgcn_s_setprio(1);
    phase_mfma<4, 0>(af, bfv0, acc);
    __builtin_amdgcn_s_setprio(0);
  }

#pragma unroll
  for (int fm = 0; fm < 8; ++fm)
#pragma unroll
    for (int fn = 0; fn < 4; ++fn)
#pragma unroll
      for (int r = 0; r < 4; ++r) {
        const int row = m0 + wm + fm * 16 + lg * 4 + r;
        const int col = n0 + wn + fn * 16 + lr;
        C[(size_t)row * N + col] = f2bf(acc[fm][fn][r]);
      }
#undef BARR
}

// ------ 256x128 2-phase GEMM (O-proj: f32 out += resid) ------
template <int FMB>
__device__ __forceinline__ void load_ao(const unsigned short* sAb, int wm,
                                        int lr, int lg, bf16x8 (&af)[2][2]) {
#pragma unroll
  for (int kk = 0; kk < 2; ++kk) {
    const int pc = kk * 4 + lg;
#pragma unroll
    for (int i = 0; i < 2; ++i) {
      const int R = wm + (FMB + i) * 16 + lr;
      const int idx = ((R >> 5) & 1) * 8192 +
                      ((((R >> 6) << 5) | (R & 31)) << 6) +
                      ((pc ^ (R & 7)) << 3);
      af[kk][i] = *(const bf16x8*)&sAb[idx];
    }
  }
}
template <int FNB>
__device__ __forceinline__ void load_bo(const unsigned short* sBb, int wn,
                                        int lr, int lg, bf16x8 (&bfv)[2][2]) {
#pragma unroll
  for (int kk = 0; kk < 2; ++kk) {
    const int pc = kk * 4 + lg;
#pragma unroll
    for (int j = 0; j < 2; ++j) {
      const int R = wn + (FNB + j) * 16 + lr;
      const int idx = ((R >> 5) & 1) * 4096 +
                      ((((R >> 6) << 5) | (R & 31)) << 6) +
                      ((pc ^ (R & 7)) << 3);
      bfv[kk][j] = *(const bf16x8*)&sBb[idx];
    }
  }
}

template <int FMB, int FNB>
__device__ __forceinline__ void phase_mfma_o(const bf16x8 (&af)[2][2],
                                             const bf16x8 (&bfv)[2][2],
                                             f32x4 (&acc)[4][4]) {
#pragma unroll
  for (int kk = 0; kk < 2; ++kk)
#pragma unroll
    for (int i = 0; i < 2; ++i)
#pragma unroll
      for (int j = 0; j < 2; ++j)
        acc[FMB + i][FNB + j] = __builtin_amdgcn_mfma_f32_16x16x32_bf16(
            af[kk][i], bfv[kk][j], acc[FMB + i][FNB + j], 0, 0, 0);
}

__global__ __launch_bounds__(512, 1) void k_gemm_ores(
    const unsigned short* __restrict__ A, const unsigned short* __restrict__ Bt,
    float* __restrict__ Cout, const float* __restrict__ resid, int M, int N,
    int K) {
  __shared__ unsigned short sA[2][256 * 64];
  __shared__ unsigned short sB[2][128 * 64];
  const int tid = threadIdx.x;
  const int w = tid >> 6;
  const int l = tid & 63;
  const int lr = l & 15, lg = l >> 4;
  const int gx = gridDim.x;
  const int lin = blockIdx.y * gx + blockIdx.x;
  const int cpx = (gx * gridDim.y) >> 3;
  const int swz = (lin & 7) * cpx + (lin >> 3);
  const int m0 = (swz / gx) * 256, n0 = (swz % gx) * 128;
  const int wm = (w >> 1) * 64, wn = (w & 1) * 64;
  f32x4 acc[4][4] = {};

  auto stageAo = [&](int t, int bufi, int h) {
    const int k0 = t * 64;
#pragma unroll
    for (int i = 0; i < 2; ++i) {
      const int L = i * 512 + tid;
      const int r = L >> 3;
      const int R = ((r >> 5) << 6) | (h << 5) | (r & 31);
      const int d = (L & 7) ^ (r & 7);
      gload_lds16(A + (size_t)(m0 + R) * K + k0 + d * 8,
                  (char*)sA[bufi] + h * 16384 +
                      (size_t)(i * 512 + w * 64) * 16);
    }
  };
  auto stageBo = [&](int t, int bufi, int h) {
    const int k0 = t * 64;
    const int L = tid;
    const int r = L >> 3;
    const int R = ((r >> 5) << 6) | (h << 5) | (r & 31);
    const int d = (L & 7) ^ (r & 7);
    gload_lds16(Bt + (size_t)(n0 + R) * K + k0 + d * 8,
                (char*)sB[bufi] + h * 8192 + (size_t)(w * 64) * 16);
  };

#define BARR()                          \
  __builtin_amdgcn_s_barrier();         \
  __builtin_amdgcn_sched_barrier(0)

  stageAo(0, 0, 0);
  stageBo(0, 0, 0);
  stageBo(0, 0, 1);
  stageAo(0, 0, 1);
  VMCNT(2);
  BARR();

  bf16x8 af[2][2];
  bf16x8 bfv0[2][2];
  bf16x8 bfv1[2][2];
  const int NT = K >> 6;
  for (int t = 0; t < NT; ++t) {
    const int bufi = t & 1;
    const int nb = bufi ^ 1;
    const bool st = (t + 1 < NT);
    load_ao<0>(sA[bufi], wm, lr, lg, af);
    load_bo<0>(sB[bufi], wn, lr, lg, bfv0);
    load_bo<2>(sB[bufi], wn, lr, lg, bfv1);
    if (st) {
      stageAo(t + 1, nb, 0);
      stageBo(t + 1, nb, 0);
    }
    __builtin_amdgcn_s_setprio(1);
    phase_mfma_o<0, 0>(af, bfv0, acc);
    phase_mfma_o<0, 2>(af, bfv1, acc);
    __builtin_amdgcn_s_setprio(0);
    if (st) {
      VMCNT(3);
    } else {
      VMCNT(0);
    }
    BARR();
    load_ao<2>(sA[bufi], wm, lr, lg, af);
    if (st) {
      stageBo(t + 1, nb, 1);
      stageAo(t + 1, nb, 1);
    }
    __builtin_amdgcn_s_setprio(1);
    phase_mfma_o<2, 2>(af, bfv1, acc);
    phase_mfma_o<2, 0>(af, bfv0, acc);
    __builtin_amdgcn_s_setprio(0);
    if (st) VMCNT(2);
    BARR();
  }

#pragma unroll
  for (int i = 0; i < 4; ++i)
#pragma unroll
    for (int j = 0; j < 4; ++j)
#pragma unroll
      for (int r = 0; r < 4; ++r) {
        const int row = m0 + wm + i * 16 + lg * 4 + r;
        const int col = n0 + wn + j * 16 + lr;
        const size_t o = (size_t)row * N + col;
        Cout[o] = acc[i][j][r] + resid[o];
      }
#undef BARR
}

// -------- phase 3 (merged): q/k norm+rope AND V->V^T in one launch -------
__global__ __launch_bounds__(256) void k_post(
    const unsigned short* __restrict__ qkv, const float* __restrict__ qw,
    const float* __restrict__ kw, const float* __restrict__ cos_t,
    const float* __restrict__ sin_t, unsigned short* __restrict__ qb,
    unsigned short* __restrict__ kb, unsigned short* __restrict__ vt_out) {
  __shared__ unsigned short tile[32][33];
  if (blockIdx.x < M_) {
    const int m = blockIdx.x;
    const int b = m >> 11, s = m & (S_ - 1);
    const int w = threadIdx.x >> 6, l = threadIdx.x & 63;
    const unsigned short* row = qkv + (size_t)m * NQKV_;
    const float c = cos_t[(size_t)m * 64 + l];
    const float sn = sin_t[(size_t)m * 64 + l];
    for (int hh = w * 6; hh < w * 6 + 6; ++hh) {
      int base, type;
      unsigned short* out;
      const float* nw;
      if (hh < NH_) {
        type = 0;
        base = hh * HD_;
        out = qb + ((size_t)(b * NH_ + hh) * S_ + s) * HD_;
        nw = qw;
      } else {
        int kh = hh - NH_;
        type = 1;
        base = NH_ * HD_ + kh * HD_;
        out = kb + ((size_t)(b * NKV_ + kh) * S_ + s) * HD_;
        nw = kw;
      }
      unsigned short r1 = row[base + l];
      unsigned short r2 = row[base + 64 + l];
      float x1 = bf2f(r1), x2 = bf2f(r2);
      float ss = x1 * x1 + x2 * x2;
#pragma unroll
      for (int mk = 1; mk < 64; mk <<= 1) ss += __shfl_xor(ss, mk);
      float sc = rsqrtf(ss * (1.0f / HD_) + 1e-6f);
      float y1 = x1 * sc * nw[l];
      float y2 = x2 * sc * nw[64 + l];
      float o1 = y1 * c - y2 * sn;
      float o2 = y2 * c + y1 * sn;
      if (type == 0) {
        o1 *= QK_SCALE;
        o2 *= QK_SCALE;
      }
      out[l] = f2bf(o1);
      out[64 + l] = f2bf(o2);
    }
  } else {
    const int n = blockIdx.x - M_;
    const int bx = n & 63, by = (n >> 6) & 3, bz = n >> 8;
    const int b = bz >> 3, kh = bz & 7;
    const unsigned short* src =
        qkv + (size_t)b * S_ * NQKV_ + (NH_ + NKV_ + kh) * HD_;
    unsigned short* dst = vt_out + (size_t)bz * S_ * HD_;
    const int tx = threadIdx.x & 31, ty = threadIdx.x >> 5;
#pragma unroll
    for (int i = ty; i < 32; i += 8)
      tile[i][tx] = src[(size_t)(bx * 32 + i) * NQKV_ + by * 32 + tx];
    __syncthreads();
#pragma unroll
    for (int i = ty; i < 32; i += 8)
      dst[(size_t)(by * 32 + i) * S_ + bx * 32 + tx] = tile[tx][i];
  }
}

// ---------------- phase 4: causal GQA flash attention --------------------
// Paired q-tiles (xa, 31-xa) share one K/V staging pass; 8 waves/512 thr.
// Grid exactly 16x32 = 512 blocks = 2/CU slots (do NOT exceed). Swapped
// QK^T, cvt_pk P pack, XOR swizzles, lane-local row-sum, fixed-max softmax.
#define MFIX 13.0f
__global__ __launch_bounds__(512, 4) void k_attn(
    const unsigned short* __restrict__ Q,   // [B*NH][S][HD] (pre-scaled)
    const unsigned short* __restrict__ K,   // [B*NKV][S][HD]
    const unsigned short* __restrict__ VT,  // [B*NKV][HD][S]
    unsigned short* __restrict__ Oa) {      // [M][NH*HD]
  __shared__ unsigned short kt[2][64 * 128];
  __shared__ unsigned short vt[2][128 * 64];
  __shared__ unsigned short pls[8 * 16 * 64];  // per-wave [16 q][64 kv]
  const int bh = blockIdx.y;
  const int b = bh >> 4, h = bh & 15;
  const int kvh = b * NKV_ + (h >> 1);
  const int xa = ((bh >> 4) & 1) ? (15 - blockIdx.x) : blockIdx.x;  // 0..15
  const int xb = 31 - xa;          // 16..31
  const int tid = threadIdx.x;
  const int w = tid >> 6, l = tid & 63;
  const int lr = l & 15, lg = l >> 4;
  const int wr = (w & 3) * 16;
  const int myx = (w < 4) ? xa : xb;
  const int q0m = myx * 64;

  bf16x8 qf[4];
  {
    const unsigned short* Qp = Q + ((size_t)bh * S_ + q0m + wr) * HD_;
#pragma unroll
    for (int tt = 0; tt < 4; ++tt)
      qf[tt] = *(const bf16x8*)(Qp + (size_t)lr * HD_ + tt * 32 + lg * 8);
  }
  f32x4 ao[8] = {};
  float lsum = 0.f;
  const unsigned short* Kp = K + (size_t)kvh * S_ * HD_;
  const unsigned short* Vp = VT + (size_t)kvh * HD_ * S_;
  unsigned short* pw = pls + w * 1024;
  const int psw = (lr & 7) << 1;

  auto stage = [&](int t, int bufi) {
    const int k0 = t * 64;
#pragma unroll
    for (int i = 0; i < 2; ++i) {
      const int chunk = i * 512 + tid;
      {
        const int r = chunk >> 4, p = chunk & 15;
        const int d = p ^ (r & 7);
        gload_lds16(Kp + (size_t)(k0 + r) * HD_ + d * 8,
                    (char*)kt[bufi] + (size_t)(i * 512 + w * 64) * 16);
      }
      {
        const int r = chunk >> 3, p = chunk & 7;
        const int d = p ^ (r & 7);
        gload_lds16(Vp + (size_t)r * S_ + k0 + d * 8,
                    (char*)vt[bufi] + (size_t)(i * 512 + w * 64) * 16);
      }
    }
  };

  auto process = [&](int t, int bufi, bool diag) {
    const unsigned short* ktb = kt[bufi];
    const unsigned short* vtb = vt[bufi];
    f32x4 sc[4] = {};
    __builtin_amdgcn_s_setprio(1);
#pragma unroll
    for (int j = 0; j < 4; ++j)
#pragma unroll
      for (int tt = 0; tt < 4; ++tt) {
        bf16x8 kf = *(const bf16x8*)&ktb[(j * 16 + lr) * 128 +
                                         (((tt * 4 + lg) ^ (lr & 7)) << 3)];
        sc[j] =
            __builtin_amdgcn_mfma_f32_16x16x32_bf16(kf, qf[tt], sc[j], 0, 0, 0);
      }
    __builtin_amdgcn_s_setprio(0);
    if (diag) {
      const int qg = q0m + wr + lr;
      const int kvb = t * 64 + lg * 4;
#pragma unroll
      for (int j = 0; j < 4; ++j)
#pragma unroll
        for (int r = 0; r < 4; ++r)
          if (kvb + j * 16 + r > qg) sc[j][r] = -1e30f;
    }
#pragma unroll
    for (int j = 0; j < 4; ++j) {
      float p0 = __expf(sc[j][0] - MFIX);
      float p1 = __expf(sc[j][1] - MFIX);
      float p2 = __expf(sc[j][2] - MFIX);
      float p3 = __expf(sc[j][3] - MFIX);
      lsum += (p0 + p1) + (p2 + p3);
      uint2 v;
      v.x = cvt_pk_bf16(p0, p1);
      v.y = cvt_pk_bf16(p2, p3);
      const int g = (4 * j + lg) ^ psw;
      *(uint2*)&pw[lr * 64 + g * 4] = v;
    }
    __builtin_amdgcn_s_setprio(1);
#pragma unroll
    for (int ks = 0; ks < 2; ++ks) {
      const int g0 = (8 * ks + 2 * lg) ^ psw;
      bf16x8 pf = *(const bf16x8*)&pw[lr * 64 + g0 * 4];
#pragma unroll
      for (int dj = 0; dj < 8; ++dj) {
        bf16x8 vf = *(const bf16x8*)&vtb[(dj * 16 + lr) * 64 +
                                         (((ks * 4 + lg) ^ (lr & 7)) << 3)];
        ao[dj] =
            __builtin_amdgcn_mfma_f32_16x16x32_bf16(vf, pf, ao[dj], 0, 0, 0);
      }
    }
    __builtin_amdgcn_s_setprio(0);
  };

  stage(0, 0);
  __syncthreads();
  int cur = 0;
  for (int t = 0; t <= xb; ++t) {
    if (t < xb) stage(t + 1, cur ^ 1);
    if (t <= myx) process(t, cur, t == myx);
    __syncthreads();
    cur ^= 1;
  }

  lsum += __shfl_xor(lsum, 16);
  lsum += __shfl_xor(lsum, 32);
  const float inv = 1.0f / lsum;
  const int sg = q0m + wr + lr;
  unsigned short* orow = Oa + ((size_t)b * S_ + sg) * (NH_ * HD_) + h * HD_;
#pragma unroll
  for (int dj = 0; dj < 8; ++dj) {
    ushort4 ov;
    ov.x = f2bf(ao[dj][0] * inv);
    ov.y = f2bf(ao[dj][1] * inv);
    ov.z = f2bf(ao[dj][2] * inv);
    ov.w = f2bf(ao[dj][3] * inv);
    *(ushort4*)&orow[dj * 16 + lg * 4] = ov;
  }
}

extern "C" void kernel_launch(void* const* d_in, const int* in_sizes, int n_in,
                              void* d_out, int out_size, void* d_ws,
                              size_t ws_size, hipStream_t stream) {
  const int* positions = (const int*)d_in[0];
  const float* hidden = (const float*)d_in[1];
  const float* residual = (const float*)d_in[2];
  const float* ln_w = (const float*)d_in[3];
  const float* qkv_w = (const float*)d_in[4];
  const float* o_w = (const float*)d_in[5];
  const float* q_nw = (const float*)d_in[6];
  const float* k_nw = (const float*)d_in[7];

  char* ws = (char*)d_ws;
  const size_t SZ_XN = (size_t)M_ * H_ * 2;            // 16 MiB
  const size_t SZ_QKVW = (size_t)NQKV_ * H_ * 2;       // 16 MiB
  const size_t SZ_OW = (size_t)H_ * (NH_ * HD_) * 2;   // 8 MiB
  const size_t SZ_QKV = (size_t)M_ * NQKV_ * 2;        // 32 MiB
  const size_t SZ_KB = (size_t)B_ * NKV_ * S_ * HD_ * 2;  // 8 MiB
  const size_t SZ_COS = (size_t)B_ * S_ * 64 * 4;      // 1 MiB

  unsigned short* xn = (unsigned short*)(ws);
  unsigned short* q_buf = (unsigned short*)(ws);            // reuse xn
  unsigned short* qkvw_bf = (unsigned short*)(ws + SZ_XN);
  unsigned short* k_buf = (unsigned short*)(ws + SZ_XN);    // reuse qkvw
  unsigned short* owbf = (unsigned short*)(ws + SZ_XN + SZ_QKVW);
  unsigned short* qkv_bf = (unsigned short*)(ws + SZ_XN + SZ_QKVW + SZ_OW);
  unsigned short* attn_o = qkv_bf;                          // reuse qkv
  unsigned short* vt_buf =
      (unsigned short*)(ws + SZ_XN + SZ_QKVW + SZ_OW + SZ_QKV);
  float* cos_t = (float*)(ws + SZ_XN + SZ_QKVW + SZ_OW + SZ_QKV + SZ_KB);
  float* sin_t = (float*)((char*)cos_t + SZ_COS);

  k_prep<<<M_ + 2048, 256, 0, stream>>>(positions, hidden, ln_w, qkv_w, o_w,
                                        xn, qkvw_bf, owbf, cos_t, sin_t);
  k_gemm256<<<dim3(NQKV_ / 256, M_ / 256), 512, 0, stream>>>(
      xn, qkvw_bf, qkv_bf, M_, NQKV_, H_);
  k_post<<<M_ + 4096, 256, 0, stream>>>(qkv_bf, q_nw, k_nw, cos_t, sin_t,
                                        q_buf, k_buf, vt_buf);
  k_attn<<<dim3(16, B_ * NH_), 512, 0, stream>>>(q_buf, k_buf, vt_buf, attn_o);
  k_gemm_ores<<<dim3((NH_ * HD_) / 128, M_ / 256), 512, 0, stream>>>(
      attn_o, owbf, (float*)d_out, residual, M_, NH_ * HD_, H_);
}